// Round 22
// baseline (834.621 us; speedup 1.0000x reference)
//
#include <hip/hip_runtime.h>
#include <math.h>

// R22 = R21 (776us) + finer batch-split on stall-bound convs (TLP lever,
//   proven twice: R12->R13 197->185, R17 178->171):
//   L12 <2,2>/8192 -> <2,1>/16384 (64 batch/blk, acc 8 VGPR);
//   L21/L22 <4,2>/2048 -> <4,1>/4096. Corner loads/block halve; ~2x resident
//   waves to cover the per-tap gather latency (L12: VALU 42%, Mfma 4.7%,
//   occ 52% -> no pipe saturated). Scratch 4MiB. All else identical to R21
//   (fused reg-sourced BN stats, fp16 activations, BN-on-load, fusions).

#define BATCH 1024
typedef unsigned short u16;
typedef unsigned int uint;
typedef _Float16 f16;
typedef __attribute__((ext_vector_type(2))) _Float16 f16x2;
typedef __attribute__((ext_vector_type(8))) _Float16 f16x8;
typedef __attribute__((ext_vector_type(4))) float f32x4;

__device__ __forceinline__ float b2f(u16 v) {
    return __uint_as_float(((uint)v) << 16);
}
__device__ __forceinline__ float ldf(const void* p, long long i, int isbf) {
    return isbf ? b2f(((const u16*)p)[i]) : ((const float*)p)[i];
}
__device__ __forceinline__ f16x2 u2h2(uint u) {
    union { uint u; f16x2 h; } c; c.u = u; return c.h;
}
__device__ __forceinline__ uint h22u(f16x2 h) {
    union { uint u; f16x2 h; } c; c.h = h; return c.u;
}
__device__ __forceinline__ float h2f(u16 v) {
    union { u16 u; f16 h; } c; c.u = v; return (float)c.h;
}
__device__ __forceinline__ u16 f2h(float f) {
    union { u16 u; f16 h; } c; c.h = (f16)f; return c.u;
}
__device__ __forceinline__ f16x2 pkh(float a, float b) {  // v_cvt_pkrtz
    union { decltype(__builtin_amdgcn_cvt_pkrtz(0.f, 0.f)) v; f16x2 h; } c;
    c.v = __builtin_amdgcn_cvt_pkrtz(a, b);
    return c.h;
}

struct Ptrs { const void* p[24]; int sz[24]; };

// ---------------- dtype probe (proven) ----------------
__global__ __launch_bounds__(256) void probe_dtype(Ptrs P, int* __restrict__ flags)
{
    int t = blockIdx.x;
    bool ones = (t == 2 || t == 5 || t == 8 || t == 11 || t == 14 || t == 17);
    bool inh  = (t == 3 || t == 6 || t == 9 || t == 12 || t == 15 || t == 18 || t == 20);
    if (inh) return;
    const u16* q = (const u16*)P.p[t];
    if (ones) {
        if (threadIdx.x == 0) {
            uint w0 = *(const uint*)q;
            flags[t] = (w0 == 0x3F803F80u) ? 1 : 0;
        }
        return;
    }
    int n = P.sz[t]; if (n > 4096) n = 4096;
    __shared__ int cnt;
    if (threadIdx.x == 0) cnt = 0;
    __syncthreads();
    int local = 0;
    for (int i = threadIdx.x; i < n; i += 256) {
        uint e = (q[i] >> 7) & 0xFFu;
        if (!(e == 0u || (e >= 100u && e <= 140u))) local++;
    }
    atomicAdd(&cnt, local);
    __syncthreads();
    if (threadIdx.x == 0) flags[t] = (cnt * 8 > n) ? 0 : 1;
}

__global__ void fixup_flags(int* __restrict__ flags)
{
    if (threadIdx.x == 0) {
        flags[3] = flags[2];  flags[6] = flags[5];  flags[9] = flags[8];
        flags[12] = flags[11]; flags[15] = flags[14]; flags[18] = flags[17];
        flags[20] = flags[19];
    }
}

// ---------------- merged sampling tables ----------------
__device__ void table_body(const void* coords, int H, int W,
                           int* tIdx, float* tW, int fcd, int i)
{
    int HW = H * W;
    if (i >= HW * 9) return;
    int p = i / 9, k = i % 9;
    int h = p / W, w = p % W;
    int kh = k / 3, kw = k % 3;
    float py = (float)(h - 1 + kh) + ldf(coords, p * 18 + 2 * k, fcd);
    float px = (float)(w - 1 + kw) + ldf(coords, p * 18 + 2 * k + 1, fcd);
    float y0f = floorf(py), x0f = floorf(px);
    float wy1 = py - y0f, wy0 = 1.0f - wy1;
    float wx1 = px - x0f, wx0 = 1.0f - wx1;
    int y0 = (int)y0f, x0 = (int)x0f;
#pragma unroll
    for (int j = 0; j < 4; ++j) {
        int dy = j >> 1, dx = j & 1;
        int yy = y0 + dy, xx = x0 + dx;
        bool valid = (yy >= 0) && (yy < H) && (xx >= 0) && (xx < W);
        int yc = min(max(yy, 0), H - 1);
        int xc = min(max(xx, 0), W - 1);
        tIdx[i * 4 + j] = yc * W + xc;
        tW[i * 4 + j] = valid ? (dy ? wy1 : wy0) * (dx ? wx1 : wx0) : 0.0f;
    }
}

__global__ __launch_bounds__(256) void build_tables(
    const void* c32, const void* c16, const void* c8,
    int* tI32, float* tW32, int* tI16, float* tW16, int* tI8, float* tW8,
    const int* __restrict__ flags)
{
    int b = blockIdx.x, t = threadIdx.x;
    if (b < 36)      table_body(c32, 32, 32, tI32, tW32, flags[21], b * 256 + t);
    else if (b < 45) table_body(c16, 16, 16, tI16, tW16, flags[22], (b - 36) * 256 + t);
    else             table_body(c8, 8, 8, tI8, tW8, flags[23], (b - 45) * 256 + t);
}

// ---------------- input transpose: x -> f16 X0[pix][b] ----------------
__global__ __launch_bounds__(256) void transpose_in(
    const void* __restrict__ x, u16* __restrict__ X0, const int* __restrict__ flags)
{
    int fx = flags[0];
    int p = blockIdx.x;
    int t = threadIdx.x;
    ushort4 v;
    v.x = f2h(ldf(x, (long long)(4 * t + 0) * 1024 + p, fx));
    v.y = f2h(ldf(x, (long long)(4 * t + 1) * 1024 + p, fx));
    v.z = f2h(ldf(x, (long long)(4 * t + 2) * 1024 + p, fx));
    v.w = f2h(ldf(x, (long long)(4 * t + 3) * 1024 + p, fx));
    ((ushort4*)(X0 + (size_t)p * BATCH))[t] = v;
}

// ---------------- merged weight prep: f16 Wb[k][c-oct][m][8c] ----------------
__device__ void wb_body(const void* W, u16* Wb, int Cout, int Cin, int fw, int i)
{
    int c8 = i & 7;
    int r = i >> 3;
    int m = r % Cout;
    int r2 = r / Cout;
    int noct = Cin >> 3;
    int oc = r2 % noct;
    int k = r2 / noct;
    int c = oc * 8 + c8;
    Wb[i] = f2h(ldf(W, (long long)m * Cin * 9 + c * 9 + k, fw));
}

__global__ __launch_bounds__(256) void prep_all(
    const void* w11, const void* w12, const void* w21, const void* w22,
    const void* w31, const void* w32,
    float* w11p, u16* wb12, u16* wb21, u16* wb22, u16* wb31, u16* wb32,
    const int* __restrict__ flags)
{
    int i = blockIdx.x * 256 + threadIdx.x;
    if (i < 288) {
        int o = i / 9, k = i % 9;
        w11p[k * 32 + o] = ldf(w11, i, flags[1]);
    } else if (i < 9504)   wb_body(w12, wb12, 32, 32, flags[4], i - 288);
    else if (i < 27936)    wb_body(w21, wb21, 64, 32, flags[7], i - 9504);
    else if (i < 64800)    wb_body(w22, wb22, 64, 64, flags[10], i - 27936);
    else if (i < 138528)   wb_body(w31, wb31, 128, 64, flags[13], i - 64800);
    else if (i < 285984)   wb_body(w32, wb32, 128, 128, flags[16], i - 138528);
}

// ---------------- reduce per-block stat partials -> stats[2c] ----------------
__global__ __launch_bounds__(256) void reduce_stats(
    const float* __restrict__ scratch, float* __restrict__ stats, int C, int nblk)
{
    int c = blockIdx.x;
    float s = 0.f, q = 0.f;
    for (int b = threadIdx.x; b < nblk; b += 256) {
        s += scratch[(size_t)b * 2 * C + 2 * c];
        q += scratch[(size_t)b * 2 * C + 2 * c + 1];
    }
#pragma unroll
    for (int d = 1; d < 64; d <<= 1) {
        s += __shfl_xor(s, d);
        q += __shfl_xor(q, d);
    }
    __shared__ float ls[4], lq[4];
    int wid = threadIdx.x >> 6, lane = threadIdx.x & 63;
    if (lane == 0) { ls[wid] = s; lq[wid] = q; }
    __syncthreads();
    if (threadIdx.x == 0) {
        stats[2 * c] = (ls[0] + ls[1]) + (ls[2] + ls[3]);
        stats[2 * c + 1] = (lq[0] + lq[1]) + (lq[2] + lq[3]);
    }
}

// ---------------- L11 VALU conv (f16 in/out) + fused stat partials ----------------
__global__ __launch_bounds__(256) void conv_l11(
    const u16* __restrict__ X0, const float* __restrict__ W2,
    u16* __restrict__ Y, const int* __restrict__ tIdx, const float* __restrict__ tW,
    float* __restrict__ scratch)
{
    const int id = blockIdx.x;
    const int p = id >> 1;
    const int oBase = (id & 1) * 16;
    const int b4 = threadIdx.x;
    const ushort4* Xu = (const ushort4*)X0;

    float4 acc[16];
#pragma unroll
    for (int o = 0; o < 16; ++o) acc[o] = make_float4(0.f, 0.f, 0.f, 0.f);

#pragma unroll
    for (int k = 0; k < 9; ++k) {
        float4 s = make_float4(0.f, 0.f, 0.f, 0.f);
#pragma unroll
        for (int j = 0; j < 4; ++j) {
            float wgt = tW[p * 36 + k * 4 + j];
            int pix = tIdx[p * 36 + k * 4 + j];
            ushort4 vv = Xu[pix * 256 + b4];
            s.x = fmaf(wgt, h2f(vv.x), s.x); s.y = fmaf(wgt, h2f(vv.y), s.y);
            s.z = fmaf(wgt, h2f(vv.z), s.z); s.w = fmaf(wgt, h2f(vv.w), s.w);
        }
#pragma unroll
        for (int o = 0; o < 16; ++o) {
            float wv = W2[k * 32 + oBase + o];
            acc[o].x = fmaf(wv, s.x, acc[o].x); acc[o].y = fmaf(wv, s.y, acc[o].y);
            acc[o].z = fmaf(wv, s.z, acc[o].z); acc[o].w = fmaf(wv, s.w, acc[o].w);
        }
    }
#pragma unroll
    for (int bb = 0; bb < 4; ++bb) {
        u16 h[16];
#pragma unroll
        for (int o = 0; o < 16; ++o) h[o] = f2h((&acc[o].x)[bb]);
        uint4 pk;
        pk.x = (uint)h[0] | ((uint)h[1] << 16);
        pk.y = (uint)h[2] | ((uint)h[3] << 16);
        pk.z = (uint)h[4] | ((uint)h[5] << 16);
        pk.w = (uint)h[6] | ((uint)h[7] << 16);
        uint4 pk2;
        pk2.x = (uint)h[8] | ((uint)h[9] << 16);
        pk2.y = (uint)h[10] | ((uint)h[11] << 16);
        pk2.z = (uint)h[12] | ((uint)h[13] << 16);
        pk2.w = (uint)h[14] | ((uint)h[15] << 16);
        size_t base = ((size_t)p * 1024 + 4 * b4 + bb) * 32 + oBase;
        *(uint4*)(Y + base) = pk;
        *(uint4*)(Y + base + 8) = pk2;
    }
    __shared__ float rS[4][16], rQ[4][16];
    int wid = threadIdx.x >> 6, lane = threadIdx.x & 63;
#pragma unroll
    for (int o = 0; o < 16; ++o) {
        float s = (acc[o].x + acc[o].y) + (acc[o].z + acc[o].w);
        float q = (acc[o].x * acc[o].x + acc[o].y * acc[o].y)
                + (acc[o].z * acc[o].z + acc[o].w * acc[o].w);
#pragma unroll
        for (int d = 1; d < 64; d <<= 1) {
            s += __shfl_xor(s, d);
            q += __shfl_xor(q, d);
        }
        if (lane == 0) { rS[wid][o] = s; rQ[wid][o] = q; }
    }
    __syncthreads();
    if (threadIdx.x < 64) {
        int c = threadIdx.x >> 1, isq = threadIdx.x & 1;
        float v = 0.f;
        if ((c >> 4) == (id & 1)) {
            int o = c & 15;
            v = isq ? (rQ[0][o] + rQ[1][o]) + (rQ[2][o] + rQ[3][o])
                    : (rS[0][o] + rS[1][o]) + (rS[2][o] + rS[3][o]);
        }
        scratch[(size_t)id * 64 + threadIdx.x] = v;
    }
}

// ---------------- MFMA conv (f16) + fused stat partials, optional BN on load ----------------
template<int MF, int NF, int BNORM>
__global__ __launch_bounds__(256) void conv_mfma(
    const u16* __restrict__ X, const u16* __restrict__ Wb,
    u16* __restrict__ Y,
    const int* __restrict__ tIdx, const float* __restrict__ tW,
    int Cin, int Cout, int HW, int pshift,
    const float* __restrict__ stats, const void* __restrict__ gamma,
    const void* __restrict__ beta, const int* __restrict__ flags,
    int gslot, int bslot, float invN, float* __restrict__ scratch)
{
    __shared__ float sSC[128], sSH[128];
    __shared__ float rS[4][128], rQ[4][128];
    if (BNORM) {
        if (threadIdx.x < Cin) {
            int c = threadIdx.x;
            float mean = stats[2 * c] * invN;
            float var = stats[2 * c + 1] * invN - mean * mean;
            float sc = ldf(gamma, c, flags[gslot]) * rsqrtf(var + 1e-5f);
            sSC[c] = sc;
            sSH[c] = ldf(beta, c, flags[bslot]) - mean * sc;
        }
        __syncthreads();
    }

    const int tid = threadIdx.x;
    const int wid = tid >> 6;
    const int lane = tid & 63;
    const int quad = lane >> 4;
    const int l16 = lane & 15;

    const int pper = HW >> 3;
    const int xcd = blockIdx.x & 7;
    const int lid = blockIdx.x >> 3;
    const int p = xcd * pper + (lid & (pper - 1));
    const int yq = lid >> pshift;

    const int nb = yq * (4 * NF * 16);
    const int wn = wid * (NF * 16);

    const int noct = Cin >> 3;
    const size_t pixstride = (size_t)1024 * Cin;

    int roff[NF];
#pragma unroll
    for (int nf = 0; nf < NF; ++nf)
        roff[nf] = (nb + wn + nf * 16 + l16) * Cin + quad * 8;

    f32x4 acc[MF][NF];
#pragma unroll
    for (int mf = 0; mf < MF; ++mf)
#pragma unroll
        for (int nf = 0; nf < NF; ++nf)
            acc[mf][nf] = (f32x4){0.f, 0.f, 0.f, 0.f};

    const f16x2 zeroh = (f16x2){(f16)0, (f16)0};
    const int nc = Cin >> 5;
    for (int cc = 0; cc < nc; ++cc) {
        const int coff = cc << 5;
        f16x2 sc2[4], sh2[4];
        if (BNORM) {
            int c0 = coff + quad * 8;
#pragma unroll
            for (int i = 0; i < 4; ++i) {
                sc2[i] = pkh(sSC[c0 + 2 * i], sSC[c0 + 2 * i + 1]);
                sh2[i] = pkh(sSH[c0 + 2 * i], sSH[c0 + 2 * i + 1]);
            }
        }
        for (int k = 0; k < 9; ++k) {
            int pix[4]; f16x2 wwh[4];
#pragma unroll
            for (int j = 0; j < 4; ++j) {
                pix[j] = __builtin_amdgcn_readfirstlane(tIdx[p * 36 + k * 4 + j]);
                float w = __uint_as_float(__builtin_amdgcn_readfirstlane(
                    __float_as_uint(tW[p * 36 + k * 4 + j])));
                wwh[j] = pkh(w, w);
            }
            const u16* xb0 = X + (size_t)pix[0] * pixstride;
            const u16* xb1 = X + (size_t)pix[1] * pixstride;
            const u16* xb2 = X + (size_t)pix[2] * pixstride;
            const u16* xb3 = X + (size_t)pix[3] * pixstride;

            f16x8 bf[NF];
#pragma unroll
            for (int nf = 0; nf < NF; ++nf) {
                int ro = roff[nf] + coff;
                uint4 v0 = *(const uint4*)(xb0 + ro);
                uint4 v1 = *(const uint4*)(xb1 + ro);
                uint4 v2 = *(const uint4*)(xb2 + ro);
                uint4 v3 = *(const uint4*)(xb3 + ro);
                const uint* a0 = &v0.x; const uint* a1 = &v1.x;
                const uint* a2 = &v2.x; const uint* a3 = &v3.x;
                union { f16x8 h; uint4 u; } cvt;
                uint o[4];
#pragma unroll
                for (int i = 0; i < 4; ++i) {
                    f16x2 t0 = u2h2(a0[i]), t1 = u2h2(a1[i]);
                    f16x2 t2 = u2h2(a2[i]), t3 = u2h2(a3[i]);
                    if (BNORM) {
                        t0 = __builtin_elementwise_max(t0 * sc2[i] + sh2[i], zeroh);
                        t1 = __builtin_elementwise_max(t1 * sc2[i] + sh2[i], zeroh);
                        t2 = __builtin_elementwise_max(t2 * sc2[i] + sh2[i], zeroh);
                        t3 = __builtin_elementwise_max(t3 * sc2[i] + sh2[i], zeroh);
                    }
                    f16x2 a = t0 * wwh[0];
                    a = t1 * wwh[1] + a;
                    a = t2 * wwh[2] + a;
                    a = t3 * wwh[3] + a;
                    o[i] = h22u(a);
                }
                cvt.u.x = o[0]; cvt.u.y = o[1]; cvt.u.z = o[2]; cvt.u.w = o[3];
                bf[nf] = cvt.h;
            }
            const u16* wk = Wb + ((size_t)(k * noct + (cc << 2) + quad) * Cout + l16) * 8;
#pragma unroll
            for (int mf = 0; mf < MF; ++mf) {
                const f16x8 af = *(const f16x8*)(wk + (size_t)mf * 16 * 8);
#pragma unroll
                for (int nf = 0; nf < NF; ++nf)
                    acc[mf][nf] = __builtin_amdgcn_mfma_f32_16x16x32_f16(
                        af, bf[nf], acc[mf][nf], 0, 0, 0);
            }
        }
    }

    // store epilogue (proven layout): C col=lane&15 (n), row=quad*4+reg (m)
#pragma unroll
    for (int mf = 0; mf < MF; ++mf) {
        int cout0 = mf * 16 + quad * 4;
#pragma unroll
        for (int nf = 0; nf < NF; ++nf) {
            int b = nb + wn + nf * 16 + l16;
            uint2 pk;
            pk.x = h22u(pkh(acc[mf][nf][0], acc[mf][nf][1]));
            pk.y = h22u(pkh(acc[mf][nf][2], acc[mf][nf][3]));
            *(uint2*)(Y + ((size_t)p * 1024 + b) * Cout + cout0) = pk;
        }
    }

    // fused stat partials (no atomics)
#pragma unroll
    for (int mf = 0; mf < MF; ++mf)
#pragma unroll
        for (int reg = 0; reg < 4; ++reg) {
            float s = 0.f, q = 0.f;
#pragma unroll
            for (int nf = 0; nf < NF; ++nf) {
                float v = acc[mf][nf][reg];
                s += v; q += v * v;
            }
#pragma unroll
            for (int d = 1; d < 16; d <<= 1) {
                s += __shfl_xor(s, d);
                q += __shfl_xor(q, d);
            }
            if (l16 == 0) {
                int c = mf * 16 + quad * 4 + reg;
                rS[wid][c] = s;
                rQ[wid][c] = q;
            }
        }
    __syncthreads();
    if (tid < 2 * Cout) {
        int c = tid >> 1, isq = tid & 1;
        float v = isq ? (rQ[0][c] + rQ[1][c]) + (rQ[2][c] + rQ[3][c])
                      : (rS[0][c] + rS[1][c]) + (rS[2][c] + rS[3][c]);
        scratch[(size_t)blockIdx.x * 2 * Cout + tid] = v;
    }
}

// ---------------- fused maxpool + BN + ReLU (f16; max-then-BN, monotone) ----------------
__global__ __launch_bounds__(256) void pool_bn(
    const u16* __restrict__ A, u16* __restrict__ P,
    const float* __restrict__ stats,
    const void* __restrict__ gamma, const void* __restrict__ beta,
    const int* __restrict__ flags, int gslot, int bslot,
    int H2, int W2, int C, float invN, long long total)
{
    __shared__ float sSC[128], sSH[128];
    if (threadIdx.x < C) {
        int c = threadIdx.x;
        float mean = stats[2 * c] * invN;
        float var = stats[2 * c + 1] * invN - mean * mean;
        float sc = ldf(gamma, c, flags[gslot]) * rsqrtf(var + 1e-5f);
        sSC[c] = sc;
        sSH[c] = ldf(beta, c, flags[bslot]) - mean * sc;
    }
    __syncthreads();
    long long i = (long long)blockIdx.x * 256 + threadIdx.x;
    if (i >= total) return;
    int cgn = C >> 3;
    int cg = (int)(i % cgn);
    long long row = i / cgn;
    int b = (int)(row & 1023);
    int p2 = (int)(row >> 10);
    int h2 = p2 / W2, w2 = p2 % W2;
    int W = 2 * W2;
    int p00 = (2 * h2) * W + 2 * w2;
    const u16* base = A + (size_t)cg * 8;
    uint4 va = *(const uint4*)(base + ((size_t)(p00)*1024 + b) * C);
    uint4 vb = *(const uint4*)(base + ((size_t)(p00 + 1) * 1024 + b) * C);
    uint4 vd = *(const uint4*)(base + ((size_t)(p00 + W) * 1024 + b) * C);
    uint4 ve = *(const uint4*)(base + ((size_t)(p00 + W + 1) * 1024 + b) * C);
    uint ra[4] = {va.x, va.y, va.z, va.w};
    uint rb[4] = {vb.x, vb.y, vb.z, vb.w};
    uint rd[4] = {vd.x, vd.y, vd.z, vd.w};
    uint re[4] = {ve.x, ve.y, ve.z, ve.w};
    uint ro[4];
#pragma unroll
    for (int j = 0; j < 4; ++j) {
        int c = cg * 8 + 2 * j;
        f16x2 ha = u2h2(ra[j]), hb = u2h2(rb[j]), hd = u2h2(rd[j]), he = u2h2(re[j]);
        f16x2 hm = __builtin_elementwise_max(
            __builtin_elementwise_max(ha, hb), __builtin_elementwise_max(hd, he));
        float lo = fmaxf(fmaf((float)hm.x, sSC[c], sSH[c]), 0.f);
        float hi = fmaxf(fmaf((float)hm.y, sSC[c + 1], sSH[c + 1]), 0.f);
        ro[j] = h22u(pkh(lo, hi));
    }
    uint4 m; m.x = ro[0]; m.y = ro[1]; m.z = ro[2]; m.w = ro[3];
    *(uint4*)(P + ((size_t)p2 * 1024 + b) * C + cg * 8) = m;
}

// ---------------- fused avgpool + BN + ReLU (f16 in) -> f32 M[b][128] ----------------
__global__ __launch_bounds__(256) void avg_bn(
    const u16* __restrict__ A, float* __restrict__ M,
    const float* __restrict__ stats,
    const void* __restrict__ gamma, const void* __restrict__ beta,
    const int* __restrict__ flags, int gslot, int bslot, float invN)
{
    __shared__ float sSC[128], sSH[128];
    if (threadIdx.x < 128) {
        int c = threadIdx.x;
        float mean = stats[2 * c] * invN;
        float var = stats[2 * c + 1] * invN - mean * mean;
        float sc = ldf(gamma, c, flags[gslot]) * rsqrtf(var + 1e-5f);
        sSC[c] = sc;
        sSH[c] = ldf(beta, c, flags[bslot]) - mean * sc;
    }
    __syncthreads();
    int i = blockIdx.x * 256 + threadIdx.x;   // b*16 + cg
    int b = i >> 4, cg = i & 15;
    float s[8];
#pragma unroll
    for (int j = 0; j < 8; ++j) s[j] = 0.f;
    for (int p = 0; p < 64; ++p) {
        uint4 v = *(const uint4*)(A + ((size_t)p * 1024 + b) * 128 + cg * 8);
        uint ua[4] = {v.x, v.y, v.z, v.w};
#pragma unroll
        for (int jj = 0; jj < 4; ++jj) {
            int c = cg * 8 + 2 * jj;
            f16x2 h = u2h2(ua[jj]);
            s[2 * jj] += fmaxf(fmaf((float)h.x, sSC[c], sSH[c]), 0.f);
            s[2 * jj + 1] += fmaxf(fmaf((float)h.y, sSC[c + 1], sSH[c + 1]), 0.f);
        }
    }
#pragma unroll
    for (int j = 0; j < 8; ++j) M[(size_t)b * 128 + cg * 8 + j] = s[j] * (1.0f / 64.0f);
}

// ---------------- FC ----------------
__global__ __launch_bounds__(256) void fc_naive(
    const float* __restrict__ M, const void* __restrict__ fcw,
    const void* __restrict__ fcb, float* __restrict__ out, int total,
    const int* __restrict__ flags)
{
    int fw = flags[19], fb = flags[20];
    int i = blockIdx.x * 256 + threadIdx.x;
    if (i >= total) return;
    int o = i % 10, b = i / 10;
    float acc = ldf(fcb, o, fb);
    const float* Mb = M + (size_t)b * 128;
    for (int c = 0; c < 128; ++c) acc = fmaf(Mb[c], ldf(fcw, (size_t)o * 128 + c, fw), acc);
    out[i] = acc;
}

__global__ __launch_bounds__(256) void sentinel_k(float* out, int n, float v) {
    int i = blockIdx.x * 256 + threadIdx.x;
    if (i < n) out[i] = v;
}

extern "C" void kernel_launch(void* const* d_in, const int* in_sizes, int n_in,
                              void* d_out, int out_size, void* d_ws, size_t ws_size,
                              hipStream_t stream) {
    float* out = (float*)d_out;

    static const int exp_sizes[24] = {
        1024 * 1024,
        288, 32, 32,   9216, 32, 32,   18432, 64, 64,   36864, 64, 64,
        73728, 128, 128,   147456, 128, 128,
        1280, 10,   18432, 4608, 1152
    };
    float bad = 0.0f;
    if (n_in != 24) bad = 1000.0f;
    else {
        for (int i = 0; i < 24; ++i)
            if (in_sizes[i] != exp_sizes[i]) { bad = 2000.0f + 16.0f * i; break; }
    }
    if (bad != 0.0f) {
        sentinel_k<<<(out_size + 255) / 256, 256, 0, stream>>>(out, out_size, bad);
        return;
    }

    Ptrs P;
    for (int i = 0; i < 24; ++i) { P.p[i] = d_in[i]; P.sz[i] = in_sizes[i]; }

    char* wsb = (char*)d_ws;
    size_t off = 0;
    auto take = [&](size_t bytes) -> void* {
        void* pp = wsb + off;
        off += (bytes + 255) & ~(size_t)255;
        return pp;
    };
    int*   flags = (int*)  take(32 * 4);
    float* stats = (float*)take(6 * 256 * 4);
    float* scr   = (float*)take((size_t)16384 * 64 * 4);   // 4 MiB partials
    int*   tI32  = (int*)  take(1024 * 36 * 4);
    float* tW32  = (float*)take(1024 * 36 * 4);
    int*   tI16  = (int*)  take(256 * 36 * 4);
    float* tW16  = (float*)take(256 * 36 * 4);
    int*   tI8   = (int*)  take(64 * 36 * 4);
    float* tW8   = (float*)take(64 * 36 * 4);
    float* w11p  = (float*)take(32 * 9 * 4);
    u16*   wb12  = (u16*)  take(32 * 32 * 9 * 2);
    u16*   wb21  = (u16*)  take(64 * 32 * 9 * 2);
    u16*   wb22  = (u16*)  take(64 * 64 * 9 * 2);
    u16*   wb31  = (u16*)  take(128 * 64 * 9 * 2);
    u16*   wb32  = (u16*)  take(128 * 128 * 9 * 2);
    u16*   X0    = (u16*)  take((size_t)1024 * BATCH * 2);
    float* M     = (float*)take((size_t)BATCH * 128 * 4);
    u16*   bufA  = (u16*)  take((size_t)32 * 1024 * BATCH * 2);   // 64 MiB
    u16*   bufB  = (u16*)  take((size_t)32 * 1024 * BATCH * 2);   // 64 MiB

    if (ws_size < off) {
        sentinel_k<<<(out_size + 255) / 256, 256, 0, stream>>>(out, out_size, 12345.0f);
        return;
    }

    probe_dtype<<<24, 256, 0, stream>>>(P, flags);
    fixup_flags<<<1, 64, 0, stream>>>(flags);
    build_tables<<<48, 256, 0, stream>>>(d_in[21], d_in[22], d_in[23],
                                         tI32, tW32, tI16, tW16, tI8, tW8, flags);
    transpose_in<<<1024, 256, 0, stream>>>(d_in[0], X0, flags);
    prep_all<<<1118, 256, 0, stream>>>(d_in[1], d_in[4], d_in[7], d_in[10], d_in[13], d_in[16],
                                       w11p, wb12, wb21, wb22, wb31, wb32, flags);

    float* st0 = stats + 0 * 256;
    float* st1 = stats + 1 * 256;
    float* st2 = stats + 2 * 256;
    float* st3 = stats + 3 * 256;
    float* st4 = stats + 4 * 256;
    float* st5 = stats + 5 * 256;

    // L11: VALU conv (raw) -> bufA [p][b][32] + partials; reduce -> st0
    conv_l11<<<2048, 256, 0, stream>>>(X0, w11p, bufA, tI32, tW32, scr);
    reduce_stats<<<32, 256, 0, stream>>>(scr, st0, 32, 2048);
    // L12: BN(st0)-on-load conv 32->32, <2,1> grid 16384 (TLP); reduce -> st1; pool+BN
    conv_mfma<2, 1, 1><<<16384, 256, 0, stream>>>(bufA, wb12, bufB, tI32, tW32, 32, 32, 1024, 7,
                                                  st0, d_in[2], d_in[3], flags, 2, 3,
                                                  1.0f / 1048576.0f, scr);
    reduce_stats<<<32, 256, 0, stream>>>(scr, st1, 32, 16384);
    pool_bn<<<4096, 256, 0, stream>>>(bufB, bufA, st1, d_in[5], d_in[6], flags, 5, 6,
                                      16, 16, 32, 1.0f / 1048576.0f, 1048576LL);
    // L21: conv 32->64 <4,1> grid 4096; reduce -> st2
    conv_mfma<4, 1, 0><<<4096, 256, 0, stream>>>(bufA, wb21, bufB, tI16, tW16, 32, 64, 256, 5,
                                                 st0, d_in[2], d_in[3], flags, 2, 3, 0.f, scr);
    reduce_stats<<<64, 256, 0, stream>>>(scr, st2, 64, 4096);
    // L22: BN(st2)-on-load conv 64->64 <4,1> grid 4096; reduce -> st3; pool+BN
    conv_mfma<4, 1, 1><<<4096, 256, 0, stream>>>(bufB, wb22, bufA, tI16, tW16, 64, 64, 256, 5,
                                                 st2, d_in[8], d_in[9], flags, 8, 9,
                                                 1.0f / 262144.0f, scr);
    reduce_stats<<<64, 256, 0, stream>>>(scr, st3, 64, 4096);
    pool_bn<<<2048, 256, 0, stream>>>(bufA, bufB, st3, d_in[11], d_in[12], flags, 11, 12,
                                      8, 8, 64, 1.0f / 262144.0f, 524288LL);
    // L31: conv 64->128 + partials; reduce -> st4
    conv_mfma<8, 1, 0><<<1024, 256, 0, stream>>>(bufB, wb31, bufA, tI8, tW8, 64, 128, 64, 3,
                                                 st0, d_in[2], d_in[3], flags, 2, 3, 0.f, scr);
    reduce_stats<<<128, 256, 0, stream>>>(scr, st4, 128, 1024);
    // L32: BN(st4)-on-load conv 128->128 + partials; reduce -> st5; avg+BN -> M
    conv_mfma<8, 1, 1><<<1024, 256, 0, stream>>>(bufA, wb32, bufB, tI8, tW8, 128, 128, 64, 3,
                                                 st4, d_in[14], d_in[15], flags, 14, 15,
                                                 1.0f / 65536.0f, scr);
    reduce_stats<<<128, 256, 0, stream>>>(scr, st5, 128, 1024);
    avg_bn<<<64, 256, 0, stream>>>(bufB, M, st5, d_in[17], d_in[18], flags, 17, 18,
                                   1.0f / 65536.0f);
    // FC
    fc_naive<<<40, 256, 0, stream>>>(M, d_in[19], d_in[20], out, 10240, flags);
}

// Round 23
// 774.450 us; speedup vs baseline: 1.0777x; 1.0777x over previous
//
#include <hip/hip_runtime.h>
#include <math.h>

// R23 = exact restore of R21 (measured best: 776us, absmax 0.0039).
//   R22 post-mortem: NF=1 split raised occupancy 52->83% but duplicated
//   A-loads/tables/epilogue per half-batch -> L12 173->198us. Batch-tile
//   knee measured: NF=4:185 / NF=2:173(best) / NF=1:198. Lever exhausted.
//   Final structure: fp16 activations, MFMA implicit-GEMM convs with
//   BN+ReLU-on-load, fused register-sourced BN stats (no atomics) +
//   tiny reduce, pool+BN / avg+BN fusions, XCD swizzle. Output f32;
//   adaptive per-tensor input dtype probe.

#define BATCH 1024
typedef unsigned short u16;
typedef unsigned int uint;
typedef _Float16 f16;
typedef __attribute__((ext_vector_type(2))) _Float16 f16x2;
typedef __attribute__((ext_vector_type(8))) _Float16 f16x8;
typedef __attribute__((ext_vector_type(4))) float f32x4;

__device__ __forceinline__ float b2f(u16 v) {
    return __uint_as_float(((uint)v) << 16);
}
__device__ __forceinline__ float ldf(const void* p, long long i, int isbf) {
    return isbf ? b2f(((const u16*)p)[i]) : ((const float*)p)[i];
}
__device__ __forceinline__ f16x2 u2h2(uint u) {
    union { uint u; f16x2 h; } c; c.u = u; return c.h;
}
__device__ __forceinline__ uint h22u(f16x2 h) {
    union { uint u; f16x2 h; } c; c.h = h; return c.u;
}
__device__ __forceinline__ float h2f(u16 v) {
    union { u16 u; f16 h; } c; c.u = v; return (float)c.h;
}
__device__ __forceinline__ u16 f2h(float f) {
    union { u16 u; f16 h; } c; c.h = (f16)f; return c.u;
}
__device__ __forceinline__ f16x2 pkh(float a, float b) {  // v_cvt_pkrtz
    union { decltype(__builtin_amdgcn_cvt_pkrtz(0.f, 0.f)) v; f16x2 h; } c;
    c.v = __builtin_amdgcn_cvt_pkrtz(a, b);
    return c.h;
}

struct Ptrs { const void* p[24]; int sz[24]; };

// ---------------- dtype probe (proven) ----------------
__global__ __launch_bounds__(256) void probe_dtype(Ptrs P, int* __restrict__ flags)
{
    int t = blockIdx.x;
    bool ones = (t == 2 || t == 5 || t == 8 || t == 11 || t == 14 || t == 17);
    bool inh  = (t == 3 || t == 6 || t == 9 || t == 12 || t == 15 || t == 18 || t == 20);
    if (inh) return;
    const u16* q = (const u16*)P.p[t];
    if (ones) {
        if (threadIdx.x == 0) {
            uint w0 = *(const uint*)q;
            flags[t] = (w0 == 0x3F803F80u) ? 1 : 0;
        }
        return;
    }
    int n = P.sz[t]; if (n > 4096) n = 4096;
    __shared__ int cnt;
    if (threadIdx.x == 0) cnt = 0;
    __syncthreads();
    int local = 0;
    for (int i = threadIdx.x; i < n; i += 256) {
        uint e = (q[i] >> 7) & 0xFFu;
        if (!(e == 0u || (e >= 100u && e <= 140u))) local++;
    }
    atomicAdd(&cnt, local);
    __syncthreads();
    if (threadIdx.x == 0) flags[t] = (cnt * 8 > n) ? 0 : 1;
}

__global__ void fixup_flags(int* __restrict__ flags)
{
    if (threadIdx.x == 0) {
        flags[3] = flags[2];  flags[6] = flags[5];  flags[9] = flags[8];
        flags[12] = flags[11]; flags[15] = flags[14]; flags[18] = flags[17];
        flags[20] = flags[19];
    }
}

// ---------------- merged sampling tables ----------------
__device__ void table_body(const void* coords, int H, int W,
                           int* tIdx, float* tW, int fcd, int i)
{
    int HW = H * W;
    if (i >= HW * 9) return;
    int p = i / 9, k = i % 9;
    int h = p / W, w = p % W;
    int kh = k / 3, kw = k % 3;
    float py = (float)(h - 1 + kh) + ldf(coords, p * 18 + 2 * k, fcd);
    float px = (float)(w - 1 + kw) + ldf(coords, p * 18 + 2 * k + 1, fcd);
    float y0f = floorf(py), x0f = floorf(px);
    float wy1 = py - y0f, wy0 = 1.0f - wy1;
    float wx1 = px - x0f, wx0 = 1.0f - wx1;
    int y0 = (int)y0f, x0 = (int)x0f;
#pragma unroll
    for (int j = 0; j < 4; ++j) {
        int dy = j >> 1, dx = j & 1;
        int yy = y0 + dy, xx = x0 + dx;
        bool valid = (yy >= 0) && (yy < H) && (xx >= 0) && (xx < W);
        int yc = min(max(yy, 0), H - 1);
        int xc = min(max(xx, 0), W - 1);
        tIdx[i * 4 + j] = yc * W + xc;
        tW[i * 4 + j] = valid ? (dy ? wy1 : wy0) * (dx ? wx1 : wx0) : 0.0f;
    }
}

__global__ __launch_bounds__(256) void build_tables(
    const void* c32, const void* c16, const void* c8,
    int* tI32, float* tW32, int* tI16, float* tW16, int* tI8, float* tW8,
    const int* __restrict__ flags)
{
    int b = blockIdx.x, t = threadIdx.x;
    if (b < 36)      table_body(c32, 32, 32, tI32, tW32, flags[21], b * 256 + t);
    else if (b < 45) table_body(c16, 16, 16, tI16, tW16, flags[22], (b - 36) * 256 + t);
    else             table_body(c8, 8, 8, tI8, tW8, flags[23], (b - 45) * 256 + t);
}

// ---------------- input transpose: x -> f16 X0[pix][b] ----------------
__global__ __launch_bounds__(256) void transpose_in(
    const void* __restrict__ x, u16* __restrict__ X0, const int* __restrict__ flags)
{
    int fx = flags[0];
    int p = blockIdx.x;
    int t = threadIdx.x;
    ushort4 v;
    v.x = f2h(ldf(x, (long long)(4 * t + 0) * 1024 + p, fx));
    v.y = f2h(ldf(x, (long long)(4 * t + 1) * 1024 + p, fx));
    v.z = f2h(ldf(x, (long long)(4 * t + 2) * 1024 + p, fx));
    v.w = f2h(ldf(x, (long long)(4 * t + 3) * 1024 + p, fx));
    ((ushort4*)(X0 + (size_t)p * BATCH))[t] = v;
}

// ---------------- merged weight prep: f16 Wb[k][c-oct][m][8c] ----------------
__device__ void wb_body(const void* W, u16* Wb, int Cout, int Cin, int fw, int i)
{
    int c8 = i & 7;
    int r = i >> 3;
    int m = r % Cout;
    int r2 = r / Cout;
    int noct = Cin >> 3;
    int oc = r2 % noct;
    int k = r2 / noct;
    int c = oc * 8 + c8;
    Wb[i] = f2h(ldf(W, (long long)m * Cin * 9 + c * 9 + k, fw));
}

__global__ __launch_bounds__(256) void prep_all(
    const void* w11, const void* w12, const void* w21, const void* w22,
    const void* w31, const void* w32,
    float* w11p, u16* wb12, u16* wb21, u16* wb22, u16* wb31, u16* wb32,
    const int* __restrict__ flags)
{
    int i = blockIdx.x * 256 + threadIdx.x;
    if (i < 288) {
        int o = i / 9, k = i % 9;
        w11p[k * 32 + o] = ldf(w11, i, flags[1]);
    } else if (i < 9504)   wb_body(w12, wb12, 32, 32, flags[4], i - 288);
    else if (i < 27936)    wb_body(w21, wb21, 64, 32, flags[7], i - 9504);
    else if (i < 64800)    wb_body(w22, wb22, 64, 64, flags[10], i - 27936);
    else if (i < 138528)   wb_body(w31, wb31, 128, 64, flags[13], i - 64800);
    else if (i < 285984)   wb_body(w32, wb32, 128, 128, flags[16], i - 138528);
}

// ---------------- reduce per-block stat partials -> stats[2c] ----------------
__global__ __launch_bounds__(256) void reduce_stats(
    const float* __restrict__ scratch, float* __restrict__ stats, int C, int nblk)
{
    int c = blockIdx.x;
    float s = 0.f, q = 0.f;
    for (int b = threadIdx.x; b < nblk; b += 256) {
        s += scratch[(size_t)b * 2 * C + 2 * c];
        q += scratch[(size_t)b * 2 * C + 2 * c + 1];
    }
#pragma unroll
    for (int d = 1; d < 64; d <<= 1) {
        s += __shfl_xor(s, d);
        q += __shfl_xor(q, d);
    }
    __shared__ float ls[4], lq[4];
    int wid = threadIdx.x >> 6, lane = threadIdx.x & 63;
    if (lane == 0) { ls[wid] = s; lq[wid] = q; }
    __syncthreads();
    if (threadIdx.x == 0) {
        stats[2 * c] = (ls[0] + ls[1]) + (ls[2] + ls[3]);
        stats[2 * c + 1] = (lq[0] + lq[1]) + (lq[2] + lq[3]);
    }
}

// ---------------- L11 VALU conv (f16 in/out) + fused stat partials ----------------
__global__ __launch_bounds__(256) void conv_l11(
    const u16* __restrict__ X0, const float* __restrict__ W2,
    u16* __restrict__ Y, const int* __restrict__ tIdx, const float* __restrict__ tW,
    float* __restrict__ scratch)
{
    const int id = blockIdx.x;
    const int p = id >> 1;
    const int oBase = (id & 1) * 16;
    const int b4 = threadIdx.x;
    const ushort4* Xu = (const ushort4*)X0;

    float4 acc[16];
#pragma unroll
    for (int o = 0; o < 16; ++o) acc[o] = make_float4(0.f, 0.f, 0.f, 0.f);

#pragma unroll
    for (int k = 0; k < 9; ++k) {
        float4 s = make_float4(0.f, 0.f, 0.f, 0.f);
#pragma unroll
        for (int j = 0; j < 4; ++j) {
            float wgt = tW[p * 36 + k * 4 + j];
            int pix = tIdx[p * 36 + k * 4 + j];
            ushort4 vv = Xu[pix * 256 + b4];
            s.x = fmaf(wgt, h2f(vv.x), s.x); s.y = fmaf(wgt, h2f(vv.y), s.y);
            s.z = fmaf(wgt, h2f(vv.z), s.z); s.w = fmaf(wgt, h2f(vv.w), s.w);
        }
#pragma unroll
        for (int o = 0; o < 16; ++o) {
            float wv = W2[k * 32 + oBase + o];
            acc[o].x = fmaf(wv, s.x, acc[o].x); acc[o].y = fmaf(wv, s.y, acc[o].y);
            acc[o].z = fmaf(wv, s.z, acc[o].z); acc[o].w = fmaf(wv, s.w, acc[o].w);
        }
    }
#pragma unroll
    for (int bb = 0; bb < 4; ++bb) {
        u16 h[16];
#pragma unroll
        for (int o = 0; o < 16; ++o) h[o] = f2h((&acc[o].x)[bb]);
        uint4 pk;
        pk.x = (uint)h[0] | ((uint)h[1] << 16);
        pk.y = (uint)h[2] | ((uint)h[3] << 16);
        pk.z = (uint)h[4] | ((uint)h[5] << 16);
        pk.w = (uint)h[6] | ((uint)h[7] << 16);
        uint4 pk2;
        pk2.x = (uint)h[8] | ((uint)h[9] << 16);
        pk2.y = (uint)h[10] | ((uint)h[11] << 16);
        pk2.z = (uint)h[12] | ((uint)h[13] << 16);
        pk2.w = (uint)h[14] | ((uint)h[15] << 16);
        size_t base = ((size_t)p * 1024 + 4 * b4 + bb) * 32 + oBase;
        *(uint4*)(Y + base) = pk;
        *(uint4*)(Y + base + 8) = pk2;
    }
    // fused BN stat partials (no atomics)
    __shared__ float rS[4][16], rQ[4][16];
    int wid = threadIdx.x >> 6, lane = threadIdx.x & 63;
#pragma unroll
    for (int o = 0; o < 16; ++o) {
        float s = (acc[o].x + acc[o].y) + (acc[o].z + acc[o].w);
        float q = (acc[o].x * acc[o].x + acc[o].y * acc[o].y)
                + (acc[o].z * acc[o].z + acc[o].w * acc[o].w);
#pragma unroll
        for (int d = 1; d < 64; d <<= 1) {
            s += __shfl_xor(s, d);
            q += __shfl_xor(q, d);
        }
        if (lane == 0) { rS[wid][o] = s; rQ[wid][o] = q; }
    }
    __syncthreads();
    if (threadIdx.x < 64) {
        int c = threadIdx.x >> 1, isq = threadIdx.x & 1;
        float v = 0.f;
        if ((c >> 4) == (id & 1)) {
            int o = c & 15;
            v = isq ? (rQ[0][o] + rQ[1][o]) + (rQ[2][o] + rQ[3][o])
                    : (rS[0][o] + rS[1][o]) + (rS[2][o] + rS[3][o]);
        }
        scratch[(size_t)id * 64 + threadIdx.x] = v;
    }
}

// ---------------- MFMA conv (f16) + fused stat partials, optional BN on load ----------------
template<int MF, int NF, int BNORM>
__global__ __launch_bounds__(256) void conv_mfma(
    const u16* __restrict__ X, const u16* __restrict__ Wb,
    u16* __restrict__ Y,
    const int* __restrict__ tIdx, const float* __restrict__ tW,
    int Cin, int Cout, int HW, int pshift,
    const float* __restrict__ stats, const void* __restrict__ gamma,
    const void* __restrict__ beta, const int* __restrict__ flags,
    int gslot, int bslot, float invN, float* __restrict__ scratch)
{
    __shared__ float sSC[128], sSH[128];
    __shared__ float rS[4][128], rQ[4][128];
    if (BNORM) {
        if (threadIdx.x < Cin) {
            int c = threadIdx.x;
            float mean = stats[2 * c] * invN;
            float var = stats[2 * c + 1] * invN - mean * mean;
            float sc = ldf(gamma, c, flags[gslot]) * rsqrtf(var + 1e-5f);
            sSC[c] = sc;
            sSH[c] = ldf(beta, c, flags[bslot]) - mean * sc;
        }
        __syncthreads();
    }

    const int tid = threadIdx.x;
    const int wid = tid >> 6;
    const int lane = tid & 63;
    const int quad = lane >> 4;
    const int l16 = lane & 15;

    const int pper = HW >> 3;
    const int xcd = blockIdx.x & 7;
    const int lid = blockIdx.x >> 3;
    const int p = xcd * pper + (lid & (pper - 1));
    const int yq = lid >> pshift;

    const int nb = yq * (4 * NF * 16);
    const int wn = wid * (NF * 16);

    const int noct = Cin >> 3;
    const size_t pixstride = (size_t)1024 * Cin;

    int roff[NF];
#pragma unroll
    for (int nf = 0; nf < NF; ++nf)
        roff[nf] = (nb + wn + nf * 16 + l16) * Cin + quad * 8;

    f32x4 acc[MF][NF];
#pragma unroll
    for (int mf = 0; mf < MF; ++mf)
#pragma unroll
        for (int nf = 0; nf < NF; ++nf)
            acc[mf][nf] = (f32x4){0.f, 0.f, 0.f, 0.f};

    const f16x2 zeroh = (f16x2){(f16)0, (f16)0};
    const int nc = Cin >> 5;
    for (int cc = 0; cc < nc; ++cc) {
        const int coff = cc << 5;
        f16x2 sc2[4], sh2[4];
        if (BNORM) {
            int c0 = coff + quad * 8;
#pragma unroll
            for (int i = 0; i < 4; ++i) {
                sc2[i] = pkh(sSC[c0 + 2 * i], sSC[c0 + 2 * i + 1]);
                sh2[i] = pkh(sSH[c0 + 2 * i], sSH[c0 + 2 * i + 1]);
            }
        }
        for (int k = 0; k < 9; ++k) {
            int pix[4]; f16x2 wwh[4];
#pragma unroll
            for (int j = 0; j < 4; ++j) {
                pix[j] = __builtin_amdgcn_readfirstlane(tIdx[p * 36 + k * 4 + j]);
                float w = __uint_as_float(__builtin_amdgcn_readfirstlane(
                    __float_as_uint(tW[p * 36 + k * 4 + j])));
                wwh[j] = pkh(w, w);
            }
            const u16* xb0 = X + (size_t)pix[0] * pixstride;
            const u16* xb1 = X + (size_t)pix[1] * pixstride;
            const u16* xb2 = X + (size_t)pix[2] * pixstride;
            const u16* xb3 = X + (size_t)pix[3] * pixstride;

            f16x8 bf[NF];
#pragma unroll
            for (int nf = 0; nf < NF; ++nf) {
                int ro = roff[nf] + coff;
                uint4 v0 = *(const uint4*)(xb0 + ro);
                uint4 v1 = *(const uint4*)(xb1 + ro);
                uint4 v2 = *(const uint4*)(xb2 + ro);
                uint4 v3 = *(const uint4*)(xb3 + ro);
                const uint* a0 = &v0.x; const uint* a1 = &v1.x;
                const uint* a2 = &v2.x; const uint* a3 = &v3.x;
                union { f16x8 h; uint4 u; } cvt;
                uint o[4];
#pragma unroll
                for (int i = 0; i < 4; ++i) {
                    f16x2 t0 = u2h2(a0[i]), t1 = u2h2(a1[i]);
                    f16x2 t2 = u2h2(a2[i]), t3 = u2h2(a3[i]);
                    if (BNORM) {
                        t0 = __builtin_elementwise_max(t0 * sc2[i] + sh2[i], zeroh);
                        t1 = __builtin_elementwise_max(t1 * sc2[i] + sh2[i], zeroh);
                        t2 = __builtin_elementwise_max(t2 * sc2[i] + sh2[i], zeroh);
                        t3 = __builtin_elementwise_max(t3 * sc2[i] + sh2[i], zeroh);
                    }
                    f16x2 a = t0 * wwh[0];
                    a = t1 * wwh[1] + a;
                    a = t2 * wwh[2] + a;
                    a = t3 * wwh[3] + a;
                    o[i] = h22u(a);
                }
                cvt.u.x = o[0]; cvt.u.y = o[1]; cvt.u.z = o[2]; cvt.u.w = o[3];
                bf[nf] = cvt.h;
            }
            const u16* wk = Wb + ((size_t)(k * noct + (cc << 2) + quad) * Cout + l16) * 8;
#pragma unroll
            for (int mf = 0; mf < MF; ++mf) {
                const f16x8 af = *(const f16x8*)(wk + (size_t)mf * 16 * 8);
#pragma unroll
                for (int nf = 0; nf < NF; ++nf)
                    acc[mf][nf] = __builtin_amdgcn_mfma_f32_16x16x32_f16(
                        af, bf[nf], acc[mf][nf], 0, 0, 0);
            }
        }
    }

    // store epilogue (proven layout): C col=lane&15 (n), row=quad*4+reg (m)
#pragma unroll
    for (int mf = 0; mf < MF; ++mf) {
        int cout0 = mf * 16 + quad * 4;
#pragma unroll
        for (int nf = 0; nf < NF; ++nf) {
            int b = nb + wn + nf * 16 + l16;
            uint2 pk;
            pk.x = h22u(pkh(acc[mf][nf][0], acc[mf][nf][1]));
            pk.y = h22u(pkh(acc[mf][nf][2], acc[mf][nf][3]));
            *(uint2*)(Y + ((size_t)p * 1024 + b) * Cout + cout0) = pk;
        }
    }

    // fused stat partials (no atomics)
#pragma unroll
    for (int mf = 0; mf < MF; ++mf)
#pragma unroll
        for (int reg = 0; reg < 4; ++reg) {
            float s = 0.f, q = 0.f;
#pragma unroll
            for (int nf = 0; nf < NF; ++nf) {
                float v = acc[mf][nf][reg];
                s += v; q += v * v;
            }
#pragma unroll
            for (int d = 1; d < 16; d <<= 1) {
                s += __shfl_xor(s, d);
                q += __shfl_xor(q, d);
            }
            if (l16 == 0) {
                int c = mf * 16 + quad * 4 + reg;
                rS[wid][c] = s;
                rQ[wid][c] = q;
            }
        }
    __syncthreads();
    if (tid < 2 * Cout) {
        int c = tid >> 1, isq = tid & 1;
        float v = isq ? (rQ[0][c] + rQ[1][c]) + (rQ[2][c] + rQ[3][c])
                      : (rS[0][c] + rS[1][c]) + (rS[2][c] + rS[3][c]);
        scratch[(size_t)blockIdx.x * 2 * Cout + tid] = v;
    }
}

// ---------------- fused maxpool + BN + ReLU (f16; max-then-BN, monotone) ----------------
__global__ __launch_bounds__(256) void pool_bn(
    const u16* __restrict__ A, u16* __restrict__ P,
    const float* __restrict__ stats,
    const void* __restrict__ gamma, const void* __restrict__ beta,
    const int* __restrict__ flags, int gslot, int bslot,
    int H2, int W2, int C, float invN, long long total)
{
    __shared__ float sSC[128], sSH[128];
    if (threadIdx.x < C) {
        int c = threadIdx.x;
        float mean = stats[2 * c] * invN;
        float var = stats[2 * c + 1] * invN - mean * mean;
        float sc = ldf(gamma, c, flags[gslot]) * rsqrtf(var + 1e-5f);
        sSC[c] = sc;
        sSH[c] = ldf(beta, c, flags[bslot]) - mean * sc;
    }
    __syncthreads();
    long long i = (long long)blockIdx.x * 256 + threadIdx.x;
    if (i >= total) return;
    int cgn = C >> 3;
    int cg = (int)(i % cgn);
    long long row = i / cgn;
    int b = (int)(row & 1023);
    int p2 = (int)(row >> 10);
    int h2 = p2 / W2, w2 = p2 % W2;
    int W = 2 * W2;
    int p00 = (2 * h2) * W + 2 * w2;
    const u16* base = A + (size_t)cg * 8;
    uint4 va = *(const uint4*)(base + ((size_t)(p00)*1024 + b) * C);
    uint4 vb = *(const uint4*)(base + ((size_t)(p00 + 1) * 1024 + b) * C);
    uint4 vd = *(const uint4*)(base + ((size_t)(p00 + W) * 1024 + b) * C);
    uint4 ve = *(const uint4*)(base + ((size_t)(p00 + W + 1) * 1024 + b) * C);
    uint ra[4] = {va.x, va.y, va.z, va.w};
    uint rb[4] = {vb.x, vb.y, vb.z, vb.w};
    uint rd[4] = {vd.x, vd.y, vd.z, vd.w};
    uint re[4] = {ve.x, ve.y, ve.z, ve.w};
    uint ro[4];
#pragma unroll
    for (int j = 0; j < 4; ++j) {
        int c = cg * 8 + 2 * j;
        f16x2 ha = u2h2(ra[j]), hb = u2h2(rb[j]), hd = u2h2(rd[j]), he = u2h2(re[j]);
        f16x2 hm = __builtin_elementwise_max(
            __builtin_elementwise_max(ha, hb), __builtin_elementwise_max(hd, he));
        float lo = fmaxf(fmaf((float)hm.x, sSC[c], sSH[c]), 0.f);
        float hi = fmaxf(fmaf((float)hm.y, sSC[c + 1], sSH[c + 1]), 0.f);
        ro[j] = h22u(pkh(lo, hi));
    }
    uint4 m; m.x = ro[0]; m.y = ro[1]; m.z = ro[2]; m.w = ro[3];
    *(uint4*)(P + ((size_t)p2 * 1024 + b) * C + cg * 8) = m;
}

// ---------------- fused avgpool + BN + ReLU (f16 in) -> f32 M[b][128] ----------------
__global__ __launch_bounds__(256) void avg_bn(
    const u16* __restrict__ A, float* __restrict__ M,
    const float* __restrict__ stats,
    const void* __restrict__ gamma, const void* __restrict__ beta,
    const int* __restrict__ flags, int gslot, int bslot, float invN)
{
    __shared__ float sSC[128], sSH[128];
    if (threadIdx.x < 128) {
        int c = threadIdx.x;
        float mean = stats[2 * c] * invN;
        float var = stats[2 * c + 1] * invN - mean * mean;
        float sc = ldf(gamma, c, flags[gslot]) * rsqrtf(var + 1e-5f);
        sSC[c] = sc;
        sSH[c] = ldf(beta, c, flags[bslot]) - mean * sc;
    }
    __syncthreads();
    int i = blockIdx.x * 256 + threadIdx.x;   // b*16 + cg
    int b = i >> 4, cg = i & 15;
    float s[8];
#pragma unroll
    for (int j = 0; j < 8; ++j) s[j] = 0.f;
    for (int p = 0; p < 64; ++p) {
        uint4 v = *(const uint4*)(A + ((size_t)p * 1024 + b) * 128 + cg * 8);
        uint ua[4] = {v.x, v.y, v.z, v.w};
#pragma unroll
        for (int jj = 0; jj < 4; ++jj) {
            int c = cg * 8 + 2 * jj;
            f16x2 h = u2h2(ua[jj]);
            s[2 * jj] += fmaxf(fmaf((float)h.x, sSC[c], sSH[c]), 0.f);
            s[2 * jj + 1] += fmaxf(fmaf((float)h.y, sSC[c + 1], sSH[c + 1]), 0.f);
        }
    }
#pragma unroll
    for (int j = 0; j < 8; ++j) M[(size_t)b * 128 + cg * 8 + j] = s[j] * (1.0f / 64.0f);
}

// ---------------- FC ----------------
__global__ __launch_bounds__(256) void fc_naive(
    const float* __restrict__ M, const void* __restrict__ fcw,
    const void* __restrict__ fcb, float* __restrict__ out, int total,
    const int* __restrict__ flags)
{
    int fw = flags[19], fb = flags[20];
    int i = blockIdx.x * 256 + threadIdx.x;
    if (i >= total) return;
    int o = i % 10, b = i / 10;
    float acc = ldf(fcb, o, fb);
    const float* Mb = M + (size_t)b * 128;
    for (int c = 0; c < 128; ++c) acc = fmaf(Mb[c], ldf(fcw, (size_t)o * 128 + c, fw), acc);
    out[i] = acc;
}

__global__ __launch_bounds__(256) void sentinel_k(float* out, int n, float v) {
    int i = blockIdx.x * 256 + threadIdx.x;
    if (i < n) out[i] = v;
}

extern "C" void kernel_launch(void* const* d_in, const int* in_sizes, int n_in,
                              void* d_out, int out_size, void* d_ws, size_t ws_size,
                              hipStream_t stream) {
    float* out = (float*)d_out;

    static const int exp_sizes[24] = {
        1024 * 1024,
        288, 32, 32,   9216, 32, 32,   18432, 64, 64,   36864, 64, 64,
        73728, 128, 128,   147456, 128, 128,
        1280, 10,   18432, 4608, 1152
    };
    float bad = 0.0f;
    if (n_in != 24) bad = 1000.0f;
    else {
        for (int i = 0; i < 24; ++i)
            if (in_sizes[i] != exp_sizes[i]) { bad = 2000.0f + 16.0f * i; break; }
    }
    if (bad != 0.0f) {
        sentinel_k<<<(out_size + 255) / 256, 256, 0, stream>>>(out, out_size, bad);
        return;
    }

    Ptrs P;
    for (int i = 0; i < 24; ++i) { P.p[i] = d_in[i]; P.sz[i] = in_sizes[i]; }

    char* wsb = (char*)d_ws;
    size_t off = 0;
    auto take = [&](size_t bytes) -> void* {
        void* pp = wsb + off;
        off += (bytes + 255) & ~(size_t)255;
        return pp;
    };
    int*   flags = (int*)  take(32 * 4);
    float* stats = (float*)take(6 * 256 * 4);
    float* scr   = (float*)take((size_t)8192 * 64 * 4);   // 2 MiB partials
    int*   tI32  = (int*)  take(1024 * 36 * 4);
    float* tW32  = (float*)take(1024 * 36 * 4);
    int*   tI16  = (int*)  take(256 * 36 * 4);
    float* tW16  = (float*)take(256 * 36 * 4);
    int*   tI8   = (int*)  take(64 * 36 * 4);
    float* tW8   = (float*)take(64 * 36 * 4);
    float* w11p  = (float*)take(32 * 9 * 4);
    u16*   wb12  = (u16*)  take(32 * 32 * 9 * 2);
    u16*   wb21  = (u16*)  take(64 * 32 * 9 * 2);
    u16*   wb22  = (u16*)  take(64 * 64 * 9 * 2);
    u16*   wb31  = (u16*)  take(128 * 64 * 9 * 2);
    u16*   wb32  = (u16*)  take(128 * 128 * 9 * 2);
    u16*   X0    = (u16*)  take((size_t)1024 * BATCH * 2);
    float* M     = (float*)take((size_t)BATCH * 128 * 4);
    u16*   bufA  = (u16*)  take((size_t)32 * 1024 * BATCH * 2);   // 64 MiB
    u16*   bufB  = (u16*)  take((size_t)32 * 1024 * BATCH * 2);   // 64 MiB

    if (ws_size < off) {
        sentinel_k<<<(out_size + 255) / 256, 256, 0, stream>>>(out, out_size, 12345.0f);
        return;
    }

    probe_dtype<<<24, 256, 0, stream>>>(P, flags);
    fixup_flags<<<1, 64, 0, stream>>>(flags);
    build_tables<<<48, 256, 0, stream>>>(d_in[21], d_in[22], d_in[23],
                                         tI32, tW32, tI16, tW16, tI8, tW8, flags);
    transpose_in<<<1024, 256, 0, stream>>>(d_in[0], X0, flags);
    prep_all<<<1118, 256, 0, stream>>>(d_in[1], d_in[4], d_in[7], d_in[10], d_in[13], d_in[16],
                                       w11p, wb12, wb21, wb22, wb31, wb32, flags);

    float* st0 = stats + 0 * 256;
    float* st1 = stats + 1 * 256;
    float* st2 = stats + 2 * 256;
    float* st3 = stats + 3 * 256;
    float* st4 = stats + 4 * 256;
    float* st5 = stats + 5 * 256;

    // L11: VALU conv (raw) -> bufA [p][b][32] + partials; reduce -> st0
    conv_l11<<<2048, 256, 0, stream>>>(X0, w11p, bufA, tI32, tW32, scr);
    reduce_stats<<<32, 256, 0, stream>>>(scr, st0, 32, 2048);
    // L12: BN(st0)-on-load conv 32->32, <2,2> grid 8192; reduce -> st1; pool+BN
    conv_mfma<2, 2, 1><<<8192, 256, 0, stream>>>(bufA, wb12, bufB, tI32, tW32, 32, 32, 1024, 7,
                                                 st0, d_in[2], d_in[3], flags, 2, 3,
                                                 1.0f / 1048576.0f, scr);
    reduce_stats<<<32, 256, 0, stream>>>(scr, st1, 32, 8192);
    pool_bn<<<4096, 256, 0, stream>>>(bufB, bufA, st1, d_in[5], d_in[6], flags, 5, 6,
                                      16, 16, 32, 1.0f / 1048576.0f, 1048576LL);
    // L21: conv 32->64 <4,2> grid 2048; reduce -> st2
    conv_mfma<4, 2, 0><<<2048, 256, 0, stream>>>(bufA, wb21, bufB, tI16, tW16, 32, 64, 256, 5,
                                                 st0, d_in[2], d_in[3], flags, 2, 3, 0.f, scr);
    reduce_stats<<<64, 256, 0, stream>>>(scr, st2, 64, 2048);
    // L22: BN(st2)-on-load conv 64->64 <4,2> grid 2048; reduce -> st3; pool+BN
    conv_mfma<4, 2, 1><<<2048, 256, 0, stream>>>(bufB, wb22, bufA, tI16, tW16, 64, 64, 256, 5,
                                                 st2, d_in[8], d_in[9], flags, 8, 9,
                                                 1.0f / 262144.0f, scr);
    reduce_stats<<<64, 256, 0, stream>>>(scr, st3, 64, 2048);
    pool_bn<<<2048, 256, 0, stream>>>(bufA, bufB, st3, d_in[11], d_in[12], flags, 11, 12,
                                      8, 8, 64, 1.0f / 262144.0f, 524288LL);
    // L31: conv 64->128 <8,1> grid 1024; reduce -> st4
    conv_mfma<8, 1, 0><<<1024, 256, 0, stream>>>(bufB, wb31, bufA, tI8, tW8, 64, 128, 64, 3,
                                                 st0, d_in[2], d_in[3], flags, 2, 3, 0.f, scr);
    reduce_stats<<<128, 256, 0, stream>>>(scr, st4, 128, 1024);
    // L32: BN(st4)-on-load conv 128->128 <8,1> grid 1024; reduce -> st5; avg+BN -> M
    conv_mfma<8, 1, 1><<<1024, 256, 0, stream>>>(bufA, wb32, bufB, tI8, tW8, 128, 128, 64, 3,
                                                 st4, d_in[14], d_in[15], flags, 14, 15,
                                                 1.0f / 65536.0f, scr);
    reduce_stats<<<128, 256, 0, stream>>>(scr, st5, 128, 1024);
    avg_bn<<<64, 256, 0, stream>>>(bufB, M, st5, d_in[17], d_in[18], flags, 17, 18,
                                   1.0f / 65536.0f);
    // FC
    fc_naive<<<40, 256, 0, stream>>>(M, d_in[19], d_in[20], out, 10240, flags);
}